// Round 3
// baseline (256.738 us; speedup 1.0000x reference)
//
#include <hip/hip_runtime.h>

// Problem constants (B=1)
#define L 512
#define CM 256
#define CZ 128
#define NC 128
#define NBINS 65

// Dtype model (evidence, rounds 0-2):
//  - inputs fp32: round-1 bf16-reads gave NaN — impossible if inputs were bf16
//    (pure FMA kernel, all in-bounds bf16 patterns finite).
//  - outputs fp32: round-2 bf16-packed writes gave absmax 1.14 > max|ref|=0.867
//    with audited-correct layout — signature of fp32 readback of packed u16.
//  - residue_index int32.
// Output = msa_rep [1,256,128,512] fp32, then pair_rep [1,128,512,512] fp32.

// Kernel 1: tiny per-position linears into fp32 workspace.
// a2[c,l] = sum_f w_a_w[c,f]*tf[f,l] + w_a_b[c] + w_p_b[c]   (pair biases folded)
// b2[c,l] = sum_f w_b_w[c,f]*tf[f,l] + w_b_b[c]
// m2[c,l] = sum_f w_m_w[c,f]*tf[f,l] + w_m_b[c]
__global__ void pre_kernel(const float* __restrict__ tf,
                           const float* __restrict__ waw,
                           const float* __restrict__ wab,
                           const float* __restrict__ wbw,
                           const float* __restrict__ wbb,
                           const float* __restrict__ wpb,
                           const float* __restrict__ wmw,
                           const float* __restrict__ wmb,
                           float* __restrict__ a2,
                           float* __restrict__ b2,
                           float* __restrict__ m2) {
    int idx = blockIdx.x * 256 + threadIdx.x;  // 0 .. 262143
    if (idx < CZ * L) {
        int c = idx >> 9, l = idx & (L - 1);
        float acc = wab[c] + wpb[c];
        #pragma unroll
        for (int f = 0; f < 20; ++f)
            acc += waw[c * 20 + f] * tf[f * L + l];
        a2[idx] = acc;
    } else if (idx < 2 * CZ * L) {
        int t = idx - CZ * L;
        int c = t >> 9, l = t & (L - 1);
        float acc = wbb[c];
        #pragma unroll
        for (int f = 0; f < 20; ++f)
            acc += wbw[c * 20 + f] * tf[f * L + l];
        b2[t] = acc;
    } else {
        int t = idx - 2 * CZ * L;   // 0 .. CM*L-1
        int c = t >> 9, l = t & (L - 1);
        float acc = wmb[c];
        #pragma unroll
        for (int f = 0; f < 20; ++f)
            acc += wmw[c * 20 + f] * tf[f * L + l];
        m2[t] = acc;
    }
}

// Kernel 2: pair_rep[c,i,j] = a2[c,i] + b2[c,j] + w_p_w[c, clip(ri[i]-ri[j],-32,32)+32]
// grid.x = CZ*L (bx = c*512 + i), 128 threads, 4 j per thread, float4 stores.
__global__ void pair_kernel(const float* __restrict__ a2,
                            const float* __restrict__ b2,
                            const float* __restrict__ wpw,
                            const int* __restrict__ ri,
                            float* __restrict__ out) {
    int bx = blockIdx.x;
    int i = bx & (L - 1);
    int c = bx >> 9;
    int j0 = threadIdx.x * 4;

    float ai = a2[c * L + i];            // biases folded in
    int rii = ri[i];
    int4 rj = *reinterpret_cast<const int4*>(&ri[j0]);
    float4 bb = *reinterpret_cast<const float4*>(&b2[c * L + j0]);

    const float* wp = &wpw[c * NBINS];
    int d0 = min(max(rii - rj.x, -32), 32) + 32;
    int d1 = min(max(rii - rj.y, -32), 32) + 32;
    int d2 = min(max(rii - rj.z, -32), 32) + 32;
    int d3 = min(max(rii - rj.w, -32), 32) + 32;

    float4 o;
    o.x = ai + bb.x + wp[d0];
    o.y = ai + bb.y + wp[d1];
    o.z = ai + bb.z + wp[d2];
    o.w = ai + bb.w + wp[d3];
    size_t base = ((size_t)c * L + i) * L + j0;
    *reinterpret_cast<float4*>(&out[base]) = o;
}

// Kernel 3: msa_rep[c,k,l] = sum_f wc[k,c,f]*mf[f,l] + wcb[k,c] + m2[c,l]
// grid.x = CM * (NC/4): bx>>5 = c, (bx&31)*4 = k0. 256 threads, 2 l per thread,
// mf columns held in registers across the 4 k iterations.
__global__ void msa_kernel(const float* __restrict__ mf,
                           const float* __restrict__ wc,
                           const float* __restrict__ wcb,
                           const float* __restrict__ m2,
                           float* __restrict__ out) {
    int bx = blockIdx.x;
    int c = bx >> 5;            // 0..255
    int k0 = (bx & 31) * 4;     // 0..124
    int l0 = threadIdx.x * 2;

    float mfa[21], mfb[21];
    #pragma unroll
    for (int f = 0; f < 21; ++f) {
        float2 u = *reinterpret_cast<const float2*>(&mf[f * L + l0]);
        mfa[f] = u.x;
        mfb[f] = u.y;
    }
    float2 mm = *reinterpret_cast<const float2*>(&m2[c * L + l0]);

    #pragma unroll
    for (int kk = 0; kk < 4; ++kk) {
        int k = k0 + kk;
        const float* w = &wc[((size_t)k * CM + c) * 21];
        float bias = wcb[k * CM + c];
        float acc0 = bias + mm.x;
        float acc1 = bias + mm.y;
        #pragma unroll
        for (int f = 0; f < 21; ++f) {
            float wf = w[f];
            acc0 += wf * mfa[f];
            acc1 += wf * mfb[f];
        }
        float2 o;
        o.x = acc0;
        o.y = acc1;
        size_t base = ((size_t)(c * NC + k)) * L + l0;
        *reinterpret_cast<float2*>(&out[base]) = o;
    }
}

extern "C" void kernel_launch(void* const* d_in, const int* in_sizes, int n_in,
                              void* d_out, int out_size, void* d_ws, size_t ws_size,
                              hipStream_t stream) {
    const float* tf  = (const float*)d_in[0];   // target_feat [1,20,512] f32
    const int*   ri  = (const int*)d_in[1];     // residue_index [1,512] i32
    const float* mf  = (const float*)d_in[2];   // msa_feat [1,21,512] f32
    const float* waw = (const float*)d_in[3];   // [128,20]
    const float* wab = (const float*)d_in[4];   // [128]
    const float* wbw = (const float*)d_in[5];   // [128,20]
    const float* wbb = (const float*)d_in[6];   // [128]
    const float* wpw = (const float*)d_in[7];   // [128,65]
    const float* wpb = (const float*)d_in[8];   // [128]
    const float* wc  = (const float*)d_in[9];   // [128,256,21]
    const float* wcb = (const float*)d_in[10];  // [128,256]
    const float* wmw = (const float*)d_in[11];  // [256,20]
    const float* wmb = (const float*)d_in[12];  // [256]

    float* out = (float*)d_out;
    float* msa_out  = out;                         // 256*128*512 elems
    float* pair_out = out + (size_t)CM * NC * L;   // 128*512*512 elems

    float* a2 = (float*)d_ws;            // CZ*L
    float* b2 = a2 + CZ * L;             // CZ*L
    float* m2 = b2 + CZ * L;             // CM*L

    // 1) precompute a', b', m' (262144 outputs)
    pre_kernel<<<dim3((2 * CZ * L + CM * L) / 256), dim3(256), 0, stream>>>(
        tf, waw, wab, wbw, wbb, wpb, wmw, wmb, a2, b2, m2);

    // 2) pair representation
    pair_kernel<<<dim3(CZ * L), dim3(128), 0, stream>>>(a2, b2, wpw, ri, pair_out);

    // 3) msa representation
    msa_kernel<<<dim3(CM * (NC / 4)), dim3(256), 0, stream>>>(mf, wc, wcb, m2, msa_out);
}

// Round 4
// 245.283 us; speedup vs baseline: 1.0467x; 1.0467x over previous
//
#include <hip/hip_runtime.h>

// Problem constants (B=1)
#define L 512
#define CM 256
#define CZ 128
#define NC 128
#define NBINS 65

// Dtype model (settled round 3): fp32 inputs/outputs, int32 residue_index.
// Output = msa_rep [1,256,128,512] fp32, then pair_rep [1,128,512,512] fp32.
// absmax 0.0039 = 1 bf16 ulp of ref max (harness ref is bf16-rounded) -> our
// fp32 arithmetic is exact modulo that.

// Kernel 1: tiny per-position linears into fp32 workspace.
// a2[c,l] = sum_f w_a_w[c,f]*tf[f,l] + w_a_b[c] + w_p_b[c]   (pair biases folded)
// b2[c,l] = sum_f w_b_w[c,f]*tf[f,l] + w_b_b[c]
// m2[c,l] = sum_f w_m_w[c,f]*tf[f,l] + w_m_b[c]
__global__ void pre_kernel(const float* __restrict__ tf,
                           const float* __restrict__ waw,
                           const float* __restrict__ wab,
                           const float* __restrict__ wbw,
                           const float* __restrict__ wbb,
                           const float* __restrict__ wpb,
                           const float* __restrict__ wmw,
                           const float* __restrict__ wmb,
                           float* __restrict__ a2,
                           float* __restrict__ b2,
                           float* __restrict__ m2) {
    int idx = blockIdx.x * 256 + threadIdx.x;  // 0 .. 262143
    if (idx < CZ * L) {
        int c = idx >> 9, l = idx & (L - 1);
        float acc = wab[c] + wpb[c];
        #pragma unroll
        for (int f = 0; f < 20; ++f)
            acc += waw[c * 20 + f] * tf[f * L + l];
        a2[idx] = acc;
    } else if (idx < 2 * CZ * L) {
        int t = idx - CZ * L;
        int c = t >> 9, l = t & (L - 1);
        float acc = wbb[c];
        #pragma unroll
        for (int f = 0; f < 20; ++f)
            acc += wbw[c * 20 + f] * tf[f * L + l];
        b2[t] = acc;
    } else {
        int t = idx - 2 * CZ * L;   // 0 .. CM*L-1
        int c = t >> 9, l = t & (L - 1);
        float acc = wmb[c];
        #pragma unroll
        for (int f = 0; f < 20; ++f)
            acc += wmw[c * 20 + f] * tf[f * L + l];
        m2[t] = acc;
    }
}

// Fused kernel: pair blocks [0, 16384) + msa blocks [16384, 24576).
// Pair block: c = bx>>7, i0 = (bx&127)*4 — covers 4 output rows (8 KB).
//   thread: half = t>>7 (row within pair), jq = t&127, j0 = jq*4; 2 iterations.
// Msa block (bx-16384 in [0,8192)): c = b>>5, k0 = (b&31)*4; 2 l per thread.
#define NPAIR_BLK (CZ * L / 4)   /* 16384 */
#define NMSA_BLK  (CM * NC / 4)  /* 8192  */

__global__ __launch_bounds__(256)
void fused_kernel(const float* __restrict__ a2,
                  const float* __restrict__ b2,
                  const float* __restrict__ wpw,
                  const int* __restrict__ ri,
                  const float* __restrict__ mf,
                  const float* __restrict__ wc,
                  const float* __restrict__ wcb,
                  const float* __restrict__ m2,
                  float* __restrict__ pair_out,
                  float* __restrict__ msa_out) {
    int bx = blockIdx.x;
    int t = threadIdx.x;

    if (bx < NPAIR_BLK) {
        // ---- pair: pair_rep[c,i,j] = a2[c,i] + b2[c,j] + wp[c, bin(ri_i-ri_j)]
        int c = bx >> 7;
        int i0 = (bx & 127) * 4;
        int half = t >> 7;          // wave-uniform (waves 0,1 -> 0; 2,3 -> 1)
        int j0 = (t & 127) * 4;

        int4 rj = *reinterpret_cast<const int4*>(&ri[j0]);
        float4 bb = *reinterpret_cast<const float4*>(&b2[c * L + j0]);
        const float* wp = &wpw[c * NBINS];

        #pragma unroll
        for (int r = 0; r < 2; ++r) {
            int i = i0 + r * 2 + half;
            float ai = a2[c * L + i];      // wave-uniform -> scalar load
            int rii = ri[i];

            int d0 = min(max(rii - rj.x, -32), 32) + 32;
            int d1 = min(max(rii - rj.y, -32), 32) + 32;
            int d2 = min(max(rii - rj.z, -32), 32) + 32;
            int d3 = min(max(rii - rj.w, -32), 32) + 32;

            float4 o;
            o.x = ai + bb.x + wp[d0];
            o.y = ai + bb.y + wp[d1];
            o.z = ai + bb.z + wp[d2];
            o.w = ai + bb.w + wp[d3];
            size_t base = ((size_t)c * L + i) * L + j0;
            *reinterpret_cast<float4*>(&pair_out[base]) = o;
        }
    } else {
        // ---- msa: msa_rep[c,k,l] = sum_f wc[k,c,f]*mf[f,l] + wcb[k,c] + m2[c,l]
        int b = bx - NPAIR_BLK;
        int c = b >> 5;             // 0..255
        int k0 = (b & 31) * 4;      // 0..124
        int l0 = t * 2;

        float mfa[21], mfb[21];
        #pragma unroll
        for (int f = 0; f < 21; ++f) {
            float2 u = *reinterpret_cast<const float2*>(&mf[f * L + l0]);
            mfa[f] = u.x;
            mfb[f] = u.y;
        }
        float2 mm = *reinterpret_cast<const float2*>(&m2[c * L + l0]);

        #pragma unroll
        for (int kk = 0; kk < 4; ++kk) {
            int k = k0 + kk;
            const float* w = &wc[((size_t)k * CM + c) * 21];  // block-uniform -> s_load
            float bias = wcb[k * CM + c];
            float acc0 = bias + mm.x;
            float acc1 = bias + mm.y;
            #pragma unroll
            for (int f = 0; f < 21; ++f) {
                float wf = w[f];
                acc0 += wf * mfa[f];
                acc1 += wf * mfb[f];
            }
            float2 o;
            o.x = acc0;
            o.y = acc1;
            size_t base = ((size_t)(c * NC + k)) * L + l0;
            *reinterpret_cast<float2*>(&msa_out[base]) = o;
        }
    }
}

extern "C" void kernel_launch(void* const* d_in, const int* in_sizes, int n_in,
                              void* d_out, int out_size, void* d_ws, size_t ws_size,
                              hipStream_t stream) {
    const float* tf  = (const float*)d_in[0];   // target_feat [1,20,512] f32
    const int*   ri  = (const int*)d_in[1];     // residue_index [1,512] i32
    const float* mf  = (const float*)d_in[2];   // msa_feat [1,21,512] f32
    const float* waw = (const float*)d_in[3];   // [128,20]
    const float* wab = (const float*)d_in[4];   // [128]
    const float* wbw = (const float*)d_in[5];   // [128,20]
    const float* wbb = (const float*)d_in[6];   // [128]
    const float* wpw = (const float*)d_in[7];   // [128,65]
    const float* wpb = (const float*)d_in[8];   // [128]
    const float* wc  = (const float*)d_in[9];   // [128,256,21]
    const float* wcb = (const float*)d_in[10];  // [128,256]
    const float* wmw = (const float*)d_in[11];  // [256,20]
    const float* wmb = (const float*)d_in[12];  // [256]

    float* out = (float*)d_out;
    float* msa_out  = out;                         // 256*128*512 elems
    float* pair_out = out + (size_t)CM * NC * L;   // 128*512*512 elems

    float* a2 = (float*)d_ws;            // CZ*L
    float* b2 = a2 + CZ * L;             // CZ*L
    float* m2 = b2 + CZ * L;             // CM*L

    // 1) precompute a', b', m' (262144 outputs, biases folded)
    pre_kernel<<<dim3((2 * CZ * L + CM * L) / 256), dim3(256), 0, stream>>>(
        tf, waw, wab, wbw, wbb, wpb, wmw, wmb, a2, b2, m2);

    // 2) fused pair + msa (24576 blocks)
    fused_kernel<<<dim3(NPAIR_BLK + NMSA_BLK), dim3(256), 0, stream>>>(
        a2, b2, wpw, ri, mf, wc, wcb, m2, pair_out, msa_out);
}